// Round 5
// baseline (346.330 us; speedup 1.0000x reference)
//
#include <hip/hip_runtime.h>

#define B_ 4
#define T_ 1024
#define D_ 256
#define O_ 256
#define NC 32   // chunks along T
#define CL 32   // chunk length (NC*CL == T_)

typedef float v4f __attribute__((ext_vector_type(4)));  // nontemporal-compatible

// ---------------- Kernel A: per-chunk sums S[b,c,d] ----------------
__global__ __launch_bounds__(256) void chunk_sums(const float* __restrict__ x,
                                                  float* __restrict__ S) {
    const int d  = threadIdx.x;          // 0..255
    const int bc = blockIdx.x;           // b*NC + c
    const int b  = bc / NC;
    const int c  = bc % NC;
    const float* xp = x + ((size_t)b * T_ + (size_t)c * CL) * D_ + d;
    float s = 0.f;
#pragma unroll
    for (int i = 0; i < CL; ++i) s += xp[(size_t)i * D_];
    S[((size_t)b * NC + c) * D_ + d] = s;
}

// ---------------- Kernel B: cm[b,t,d] = cumsum(x)/(t+1) ----------------
__global__ __launch_bounds__(256) void cumsum_mean(const float* __restrict__ x,
                                                   const float* __restrict__ S,
                                                   float* __restrict__ cm) {
    const int d  = threadIdx.x;
    const int bc = blockIdx.x;
    const int b  = bc / NC;
    const int c  = bc % NC;
    float off = 0.f;
#pragma unroll
    for (int cc = 0; cc < NC; ++cc) {      // 32 independent loads, one latency
        const float v = S[((size_t)b * NC + cc) * D_ + d];
        off += (cc < c) ? v : 0.f;
    }
    const float* xp = x  + ((size_t)b * T_ + (size_t)c * CL) * D_ + d;
    float*       cp = cm + ((size_t)b * T_ + (size_t)c * CL) * D_ + d;
    float run = off;
#pragma unroll 4
    for (int i = 0; i < CL; ++i) {
        run += xp[(size_t)i * D_];
        const int t = c * CL + i;
        cp[(size_t)i * D_] = run / (float)(t + 1);   // IEEE divide, matches ref
    }
}

// ---------------- Kernel C: out[b,t,:] = cm[b,t,:] @ W[t] ----------------
// Grid 512 blocks (2/CU -> 8 waves/CU). Block = 2 t-rows x 2 d-halves.
// Wave (tq,h) streams the contiguous 128 KB half W[t0+tq][h*128.., :] with a
// 4-deep ring (24 NT loads in flight). 2-way d-reduction via transposed LDS.
__global__ __launch_bounds__(256, 2) void gemm_t(const float* __restrict__ cm,
                                                 const float* __restrict__ W,
                                                 float* __restrict__ out) {
    const int t0  = blockIdx.x * 2;
    const int tid = threadIdx.x;
    const int wv  = tid >> 6;       // 0..3
    const int tq  = wv >> 1;        // t within block
    const int h   = wv & 1;         // d-half
    const int oq  = tid & 63;       // o-quad, o = oq*4

    __shared__ float cml[2][D_][4];   // [tq][d][b], 8 KB; wave-uniform b128 reads
    __shared__ float red[2][16][64];  // [tq][k][oq] transposed: lane stride 1, 8 KB

    // Stage cm rows t0, t0+1 (coalesced over d)
#pragma unroll
    for (int q = 0; q < 2; ++q)
#pragma unroll
        for (int b = 0; b < 4; ++b)
            cml[q][tid][b] = cm[((size_t)b * T_ + t0 + q) * D_ + tid];
    __syncthreads();

    const v4f* Wp = (const v4f*)(W + ((size_t)(t0 + tq) * D_ + (size_t)h * 128) * O_) + oq;

    v4f a0 = (v4f)(0.f), a1 = (v4f)(0.f), a2 = (v4f)(0.f), a3 = (v4f)(0.f);

    v4f w[4][8];                      // ring buffer: 3 stages ahead + 1 computing
    // preload stages 0..2 (d-offsets 0..23 within the half)
#pragma unroll
    for (int st = 0; st < 3; ++st)
#pragma unroll
        for (int j = 0; j < 8; ++j)
            w[st][j] = __builtin_nontemporal_load(Wp + (size_t)(st * 8 + j) * (O_ / 4));

    // 16 stages of 8 d; fully unrolled so ring indices are static
#pragma unroll
    for (int s = 0; s < 16; ++s) {
        const int ld = s + 3;
        if (ld < 16) {
#pragma unroll
            for (int j = 0; j < 8; ++j)
                w[ld & 3][j] =
                    __builtin_nontemporal_load(Wp + (size_t)(ld * 8 + j) * (O_ / 4));
        }
        const int db = h * 128 + s * 8;
#pragma unroll
        for (int j = 0; j < 8; ++j) {
            const v4f c4 = *(const v4f*)cml[tq][db + j];   // wave-uniform broadcast
            a0 += c4.x * w[s & 3][j];
            a1 += c4.y * w[s & 3][j];
            a2 += c4.z * w[s & 3][j];
            a3 += c4.w * w[s & 3][j];
        }
    }

    // 2-way reduction: h=1 waves publish, h=0 waves combine + store.
    if (h == 1) {
        red[tq][ 0][oq] = a0.x; red[tq][ 1][oq] = a0.y; red[tq][ 2][oq] = a0.z; red[tq][ 3][oq] = a0.w;
        red[tq][ 4][oq] = a1.x; red[tq][ 5][oq] = a1.y; red[tq][ 6][oq] = a1.z; red[tq][ 7][oq] = a1.w;
        red[tq][ 8][oq] = a2.x; red[tq][ 9][oq] = a2.y; red[tq][10][oq] = a2.z; red[tq][11][oq] = a2.w;
        red[tq][12][oq] = a3.x; red[tq][13][oq] = a3.y; red[tq][14][oq] = a3.z; red[tq][15][oq] = a3.w;
    }
    __syncthreads();
    if (h == 0) {
        a0.x += red[tq][ 0][oq]; a0.y += red[tq][ 1][oq]; a0.z += red[tq][ 2][oq]; a0.w += red[tq][ 3][oq];
        a1.x += red[tq][ 4][oq]; a1.y += red[tq][ 5][oq]; a1.z += red[tq][ 6][oq]; a1.w += red[tq][ 7][oq];
        a2.x += red[tq][ 8][oq]; a2.y += red[tq][ 9][oq]; a2.z += red[tq][10][oq]; a2.w += red[tq][11][oq];
        a3.x += red[tq][12][oq]; a3.y += red[tq][13][oq]; a3.z += red[tq][14][oq]; a3.w += red[tq][15][oq];
        const size_t obase = (size_t)(t0 + tq) * O_ + (size_t)oq * 4;
        __builtin_nontemporal_store(a0, (v4f*)&out[(size_t)0 * T_ * O_ + obase]);
        __builtin_nontemporal_store(a1, (v4f*)&out[(size_t)1 * T_ * O_ + obase]);
        __builtin_nontemporal_store(a2, (v4f*)&out[(size_t)2 * T_ * O_ + obase]);
        __builtin_nontemporal_store(a3, (v4f*)&out[(size_t)3 * T_ * O_ + obase]);
    }
}

extern "C" void kernel_launch(void* const* d_in, const int* in_sizes, int n_in,
                              void* d_out, int out_size, void* d_ws, size_t ws_size,
                              hipStream_t stream) {
    const float* x = (const float*)d_in[0];   // (B,T,D) f32
    const float* W = (const float*)d_in[1];   // (T,D,O) f32
    float* out = (float*)d_out;               // (B,T,O) f32

    float* cm = (float*)d_ws;                        // B*T*D floats = 4 MB
    float* S  = (float*)d_ws + (size_t)B_ * T_ * D_; // B*NC*D floats = 128 KB

    chunk_sums <<<B_ * NC, 256, 0, stream>>>(x, S);
    cumsum_mean<<<B_ * NC, 256, 0, stream>>>(x, S, cm);
    gemm_t     <<<T_ / 2,  256, 0, stream>>>(cm, W, out);
}